// Round 1
// baseline (381.878 us; speedup 1.0000x reference)
//
#include <hip/hip_runtime.h>

#define NB   256            // batch
#define NSQ  64             // squares used (rows 3..66)
#define NH   1024           // hidden
#define ND   256            // proj dim
#define NV   1858           // moves
#define M_   (NB * NSQ)     // 16384 GEMM rows
#define N_   512            // fp|tp concat
#define K_   1024

typedef __attribute__((ext_vector_type(4))) float f32x4;
typedef __attribute__((ext_vector_type(8))) short bf16x8;

__device__ __forceinline__ unsigned short bf16_rne(float x) {
    unsigned u = __float_as_uint(x);
    unsigned r = u + 0x7fffu + ((u >> 16) & 1u);
    return (unsigned short)(r >> 16);
}

__device__ __forceinline__ void gload16(const void* g, void* l) {
    __builtin_amdgcn_global_load_lds(
        (const __attribute__((address_space(1))) unsigned int*)g,
        (__attribute__((address_space(3))) unsigned int*)l, 16, 0, 0);
}

// ---- cast hidden rows 3..66 of each b into Ahi/Alo (bf16 split), [M_][K_] ----
__global__ __launch_bounds__(256) void cast_A_kernel(
    const float* __restrict__ hid,
    unsigned short* __restrict__ Ahi, unsigned short* __restrict__ Alo) {
    int idx = blockIdx.x * 256 + threadIdx.x;   // float4 index, M_*256 total
    int m = idx >> 8;
    int q = idx & 255;
    int b = m >> 6, s = m & 63;
    const float4* src = (const float4*)(hid + (size_t)(b * 128 + 3 + s) * NH);
    float4 v = src[q];
    float vv[4] = {v.x, v.y, v.z, v.w};
    unsigned short hh[4], ll[4];
#pragma unroll
    for (int j = 0; j < 4; ++j) {
        hh[j] = bf16_rne(vv[j]);
        float hf = __uint_as_float((unsigned)hh[j] << 16);
        ll[j] = bf16_rne(vv[j] - hf);
    }
    ushort4 h = make_ushort4(hh[0], hh[1], hh[2], hh[3]);
    ushort4 l = make_ushort4(ll[0], ll[1], ll[2], ll[3]);
    ((ushort4*)Ahi)[idx] = h;
    ((ushort4*)Alo)[idx] = l;
}

// ---- cast [Wf;Wt] into Whi/Wlo, [N_][K_] ----
__global__ __launch_bounds__(256) void cast_W_kernel(
    const float* __restrict__ Wf, const float* __restrict__ Wt,
    unsigned short* __restrict__ Whi, unsigned short* __restrict__ Wlo) {
    int idx = blockIdx.x * 256 + threadIdx.x;   // 0 .. 512*256-1
    int n = idx >> 8, q = idx & 255;
    const float* srow = (n < ND) ? (Wf + (size_t)n * NH) : (Wt + (size_t)(n - ND) * NH);
    float4 v = ((const float4*)srow)[q];
    float vv[4] = {v.x, v.y, v.z, v.w};
    unsigned short hh[4], ll[4];
#pragma unroll
    for (int j = 0; j < 4; ++j) {
        hh[j] = bf16_rne(vv[j]);
        float hf = __uint_as_float((unsigned)hh[j] << 16);
        ll[j] = bf16_rne(vv[j] - hf);
    }
    ((ushort4*)Whi)[idx] = make_ushort4(hh[0], hh[1], hh[2], hh[3]);
    ((ushort4*)Wlo)[idx] = make_ushort4(ll[0], ll[1], ll[2], ll[3]);
}

// ---- gp[b][d] = hidden[b][0][:] . Wg[d][:] + bg[d], fp32 exact ----
__global__ __launch_bounds__(256) void gp_kernel(
    const float* __restrict__ hid, const float* __restrict__ Wg,
    const float* __restrict__ bg, float* __restrict__ gp) {
    __shared__ float h[NH];
    int b = blockIdx.x;
    int tid = threadIdx.x;
    ((float4*)h)[tid] = ((const float4*)(hid + (size_t)b * 128 * NH))[tid];
    __syncthreads();
    int wave = tid >> 6, lane = tid & 63;
    const float4* hs = (const float4*)h;
    for (int dd = 0; dd < 64; ++dd) {
        int d = wave * 64 + dd;
        const float4* wrow = (const float4*)(Wg + (size_t)d * NH);
        float acc = 0.f;
#pragma unroll
        for (int p = 0; p < 4; ++p) {
            float4 w = wrow[p * 64 + lane];
            float4 x = hs[p * 64 + lane];
            acc += w.x * x.x + w.y * x.y + w.z * x.z + w.w * x.w;
        }
#pragma unroll
        for (int o = 32; o > 0; o >>= 1) acc += __shfl_xor(acc, o, 64);
        if (lane == 0) gp[(size_t)b * ND + d] = acc + bg[d];
    }
}

// ---- 3-term split-bf16 GEMM: C[m][n] = sum_k A[m][k]*W[n][k] + bias[n] ----
// 128x128 tile, BK=32, 4 waves, m97 structure with global_load_lds(16B)
__global__ __launch_bounds__(256) void gemm3_kernel(
    const unsigned short* __restrict__ Ahi, const unsigned short* __restrict__ Alo,
    const unsigned short* __restrict__ Whi, const unsigned short* __restrict__ Wlo,
    const float* __restrict__ bfv, const float* __restrict__ btv,
    float* __restrict__ C) {
    __shared__ unsigned short lAh[128 * 32], lAl[128 * 32];
    __shared__ unsigned short lBh[128 * 32], lBl[128 * 32];
    int tid = threadIdx.x;
    int bid = blockIdx.x;
    int nt = bid & 3;        // 4 n-tiles
    int mt = bid >> 2;       // 128 m-tiles
    const unsigned short* gAh = Ahi + (size_t)mt * 128 * K_;
    const unsigned short* gAl = Alo + (size_t)mt * 128 * K_;
    const unsigned short* gBh = Whi + (size_t)nt * 128 * K_;
    const unsigned short* gBl = Wlo + (size_t)nt * 128 * K_;
    int lane = tid & 63, wv = tid >> 6;
    int wm = (wv >> 1) * 64, wn = (wv & 1) * 64;
    int fr = lane & 15, kh = lane >> 4;
    f32x4 acc[4][4] = {};

    for (int kt = 0; kt < K_; kt += 32) {
#pragma unroll
        for (int is = 0; is < 2; ++is) {
            int o = is * 4096 + tid * 16;       // byte offset in 8KB tile
            int r = o >> 6;                      // row 0..127
            int c = (o & 63) >> 1;               // ushort col in row
            size_t ge = (size_t)r * K_ + kt + c;
            gload16(gAh + ge, (char*)lAh + o);
            gload16(gAl + ge, (char*)lAl + o);
            gload16(gBh + ge, (char*)lBh + o);
            gload16(gBl + ge, (char*)lBl + o);
        }
        __syncthreads();
        bf16x8 ah[4], al[4], bh[4], bl[4];
#pragma unroll
        for (int f = 0; f < 4; ++f) {
            int ea = (wm + f * 16 + fr) * 32 + kh * 8;
            int eb = (wn + f * 16 + fr) * 32 + kh * 8;
            ah[f] = *(const bf16x8*)&lAh[ea];
            al[f] = *(const bf16x8*)&lAl[ea];
            bh[f] = *(const bf16x8*)&lBh[eb];
            bl[f] = *(const bf16x8*)&lBl[eb];
        }
#pragma unroll
        for (int i = 0; i < 4; ++i)
#pragma unroll
            for (int j = 0; j < 4; ++j) {
                acc[i][j] = __builtin_amdgcn_mfma_f32_16x16x32_bf16(ah[i], bh[j], acc[i][j], 0, 0, 0);
                acc[i][j] = __builtin_amdgcn_mfma_f32_16x16x32_bf16(ah[i], bl[j], acc[i][j], 0, 0, 0);
                acc[i][j] = __builtin_amdgcn_mfma_f32_16x16x32_bf16(al[i], bh[j], acc[i][j], 0, 0, 0);
            }
        __syncthreads();
    }

    const float* bias = (nt < 2) ? bfv : btv;
    int nb0 = nt * 128 - ((nt < 2) ? 0 : 256);
#pragma unroll
    for (int j = 0; j < 4; ++j) {
        int ncol = nt * 128 + wn + j * 16 + fr;
        float bv = bias[nb0 + wn + j * 16 + fr];
#pragma unroll
        for (int i = 0; i < 4; ++i) {
            int mrow = mt * 128 + wm + i * 16 + kh * 4;
#pragma unroll
            for (int r = 0; r < 4; ++r) {
                C[(size_t)(mrow + r) * N_ + ncol] = acc[i][j][r] + bv;
            }
        }
    }
}

// ---- gather + relu-dot: out[b][v] ----
__global__ __launch_bounds__(1024) void out_kernel(
    const float* __restrict__ C, const float* __restrict__ gp,
    const float* __restrict__ promo_tab, const float* __restrict__ Wsv,
    const float* __restrict__ bsv,
    const int* __restrict__ from_sqs, const int* __restrict__ to_sqs,
    const int* __restrict__ ptypes, float* __restrict__ out) {
    __shared__ float cb[NSQ * N_];       // 128 KB: fp|tp rows of this b
    __shared__ float gpl[ND];
    __shared__ float wsl[ND];
    __shared__ float pl[5 * ND];
    int b = blockIdx.x;
    int tid = threadIdx.x;
    const float4* src = (const float4*)(C + (size_t)b * NSQ * N_);
    float4* dst = (float4*)cb;
#pragma unroll
    for (int i = 0; i < 8; ++i) dst[tid + i * 1024] = src[tid + i * 1024];
    if (tid < 64) ((float4*)gpl)[tid] = ((const float4*)(gp + (size_t)b * ND))[tid];
    else if (tid < 128) ((float4*)wsl)[tid - 64] = ((const float4*)Wsv)[tid - 64];
    else if (tid < 448) ((float4*)pl)[tid - 128] = ((const float4*)promo_tab)[tid - 128];
    __syncthreads();

    int wave = tid >> 6, lane = tid & 63;
    float bias0 = bsv[0];
    const float4* cb4 = (const float4*)cb;
    const float4* gp4 = (const float4*)gpl;
    const float4* ws4 = (const float4*)wsl;
    const float4* pl4 = (const float4*)pl;
    for (int v = wave; v < NV; v += 16) {
        int sf = from_sqs[v];
        int st = to_sqs[v];
        int p  = ptypes[v];
        float4 a = cb4[sf * 128 + lane];           // fp cols 0..255
        float4 t = cb4[st * 128 + 64 + lane];      // tp cols 256..511
        float4 g = gp4[lane];
        float4 pp = pl4[p * 64 + lane];
        float4 w = ws4[lane];
        float c0 = a.x * t.x + g.x + pp.x;
        float c1 = a.y * t.y + g.y + pp.y;
        float c2 = a.z * t.z + g.z + pp.z;
        float c3 = a.w * t.w + g.w + pp.w;
        float s = fmaxf(c0, 0.f) * w.x + fmaxf(c1, 0.f) * w.y +
                  fmaxf(c2, 0.f) * w.z + fmaxf(c3, 0.f) * w.w;
#pragma unroll
        for (int o = 32; o > 0; o >>= 1) s += __shfl_xor(s, o, 64);
        if (lane == 0) out[(size_t)b * NV + v] = s + bias0;
    }
}

extern "C" void kernel_launch(void* const* d_in, const int* in_sizes, int n_in,
                              void* d_out, int out_size, void* d_ws, size_t ws_size,
                              hipStream_t stream) {
    (void)in_sizes; (void)n_in; (void)out_size; (void)ws_size;
    const float* hid   = (const float*)d_in[0];
    const float* Wf    = (const float*)d_in[1];
    const float* bfv   = (const float*)d_in[2];
    const float* Wt    = (const float*)d_in[3];
    const float* btv   = (const float*)d_in[4];
    const float* Wg    = (const float*)d_in[5];
    const float* bgv   = (const float*)d_in[6];
    const float* promo = (const float*)d_in[7];
    const float* Wsv   = (const float*)d_in[8];
    const float* bsv   = (const float*)d_in[9];
    const int* from_sqs = (const int*)d_in[10];
    const int* to_sqs   = (const int*)d_in[11];
    const int* ptypes   = (const int*)d_in[12];
    float* out = (float*)d_out;

    char* ws = (char*)d_ws;
    // layout: Ahi 32MiB | Alo 32MiB | Whi 1MiB | Wlo 1MiB | C 32MiB | gp 256KiB
    unsigned short* Ahi = (unsigned short*)(ws);
    unsigned short* Alo = (unsigned short*)(ws + 33554432);
    unsigned short* Whi = (unsigned short*)(ws + 67108864);
    unsigned short* Wlo = (unsigned short*)(ws + 68157440);
    float* C  = (float*)(ws + 69206016);
    float* gp = (float*)(ws + 102760448);

    cast_A_kernel<<<16384, 256, 0, stream>>>(hid, Ahi, Alo);
    cast_W_kernel<<<512, 256, 0, stream>>>(Wf, Wt, Whi, Wlo);
    gp_kernel<<<256, 256, 0, stream>>>(hid, Wg, bgv, gp);
    gemm3_kernel<<<512, 256, 0, stream>>>(Ahi, Alo, Whi, Wlo, bfv, btv, C);
    out_kernel<<<256, 1024, 0, stream>>>(C, gp, promo, Wsv, bsv,
                                         from_sqs, to_sqs, ptypes, out);
}

// Round 3
// 330.119 us; speedup vs baseline: 1.1568x; 1.1568x over previous
//
#include <hip/hip_runtime.h>

#define NB   256            // batch
#define NSQ  64             // squares used (rows 3..66)
#define NH   1024           // hidden
#define ND   256            // proj dim
#define NV   1858           // moves
#define M_   (NB * NSQ)     // 16384 GEMM rows
#define N_   512            // fp|tp concat
#define K_   1024

typedef __attribute__((ext_vector_type(4))) float f32x4;
typedef __attribute__((ext_vector_type(8))) short bf16x8;

__device__ __forceinline__ unsigned short bf16_rne(float x) {
    unsigned u = __float_as_uint(x);
    unsigned r = u + 0x7fffu + ((u >> 16) & 1u);
    return (unsigned short)(r >> 16);
}

__device__ __forceinline__ void gload16(const void* g, void* l) {
    __builtin_amdgcn_global_load_lds(
        (const __attribute__((address_space(1))) unsigned int*)g,
        (__attribute__((address_space(3))) unsigned int*)l, 16, 0, 0);
}

// ---- fused cast: hidden rows 3..66 -> Ahi/Alo, [Wf;Wt] -> Whi/Wlo ----
__global__ __launch_bounds__(256) void cast_kernel(
    const float* __restrict__ hid,
    const float* __restrict__ Wf, const float* __restrict__ Wt,
    unsigned short* __restrict__ Ahi, unsigned short* __restrict__ Alo,
    unsigned short* __restrict__ Whi, unsigned short* __restrict__ Wlo) {
    int bidx = blockIdx.x;
    if (bidx < 16384) {
        int idx = bidx * 256 + threadIdx.x;   // float4 index, M_*256 total
        int m = idx >> 8;
        int q = idx & 255;
        int b = m >> 6, s = m & 63;
        const float4* src = (const float4*)(hid + (size_t)(b * 128 + 3 + s) * NH);
        float4 v = src[q];
        float vv[4] = {v.x, v.y, v.z, v.w};
        unsigned short hh[4], ll[4];
#pragma unroll
        for (int j = 0; j < 4; ++j) {
            hh[j] = bf16_rne(vv[j]);
            float hf = __uint_as_float((unsigned)hh[j] << 16);
            ll[j] = bf16_rne(vv[j] - hf);
        }
        ((ushort4*)Ahi)[idx] = make_ushort4(hh[0], hh[1], hh[2], hh[3]);
        ((ushort4*)Alo)[idx] = make_ushort4(ll[0], ll[1], ll[2], ll[3]);
    } else {
        int idx = (bidx - 16384) * 256 + threadIdx.x;   // 0 .. 512*256-1
        int n = idx >> 8, q = idx & 255;
        const float* srow = (n < ND) ? (Wf + (size_t)n * NH) : (Wt + (size_t)(n - ND) * NH);
        float4 v = ((const float4*)srow)[q];
        float vv[4] = {v.x, v.y, v.z, v.w};
        unsigned short hh[4], ll[4];
#pragma unroll
        for (int j = 0; j < 4; ++j) {
            hh[j] = bf16_rne(vv[j]);
            float hf = __uint_as_float((unsigned)hh[j] << 16);
            ll[j] = bf16_rne(vv[j] - hf);
        }
        ((ushort4*)Whi)[idx] = make_ushort4(hh[0], hh[1], hh[2], hh[3]);
        ((ushort4*)Wlo)[idx] = make_ushort4(ll[0], ll[1], ll[2], ll[3]);
    }
}

// ---- gp[b][d] = hidden[b][0][:] . Wg[d][:] + bg[d], fp32 exact ----
// 1024 threads = 16 waves/CU (was 4): latency hiding for the serial d-loop.
__global__ __launch_bounds__(1024) void gp_kernel(
    const float* __restrict__ hid, const float* __restrict__ Wg,
    const float* __restrict__ bg, float* __restrict__ gp) {
    __shared__ float h[NH];
    int b = blockIdx.x;
    int tid = threadIdx.x;
    if (tid < 256) ((float4*)h)[tid] = ((const float4*)(hid + (size_t)b * 128 * NH))[tid];
    __syncthreads();
    int wave = tid >> 6, lane = tid & 63;
    const float4* hs = (const float4*)h;
    for (int dd = 0; dd < 16; ++dd) {
        int d = wave * 16 + dd;
        const float4* wrow = (const float4*)(Wg + (size_t)d * NH);
        float acc = 0.f;
#pragma unroll
        for (int p = 0; p < 4; ++p) {
            float4 w = wrow[p * 64 + lane];
            float4 x = hs[p * 64 + lane];
            acc += w.x * x.x + w.y * x.y + w.z * x.z + w.w * x.w;
        }
#pragma unroll
        for (int o = 32; o > 0; o >>= 1) acc += __shfl_xor(acc, o, 64);
        if (lane == 0) gp[(size_t)b * ND + d] = acc + bg[d];
    }
}

// ---- 3-term split-bf16 GEMM: C[m][n] = sum_k A[m][k]*W[n][k] + bias[n] ----
// 128x128 tile, BK=32, 4 waves, m97 structure with global_load_lds(16B)
__global__ __launch_bounds__(256) void gemm3_kernel(
    const unsigned short* __restrict__ Ahi, const unsigned short* __restrict__ Alo,
    const unsigned short* __restrict__ Whi, const unsigned short* __restrict__ Wlo,
    const float* __restrict__ bfv, const float* __restrict__ btv,
    float* __restrict__ C) {
    __shared__ unsigned short lAh[128 * 32], lAl[128 * 32];
    __shared__ unsigned short lBh[128 * 32], lBl[128 * 32];
    int tid = threadIdx.x;
    int bid = blockIdx.x;
    int nt = bid & 3;        // 4 n-tiles
    int mt = bid >> 2;       // 128 m-tiles
    const unsigned short* gAh = Ahi + (size_t)mt * 128 * K_;
    const unsigned short* gAl = Alo + (size_t)mt * 128 * K_;
    const unsigned short* gBh = Whi + (size_t)nt * 128 * K_;
    const unsigned short* gBl = Wlo + (size_t)nt * 128 * K_;
    int lane = tid & 63, wv = tid >> 6;
    int wm = (wv >> 1) * 64, wn = (wv & 1) * 64;
    int fr = lane & 15, kh = lane >> 4;
    f32x4 acc[4][4] = {};

    for (int kt = 0; kt < K_; kt += 32) {
#pragma unroll
        for (int is = 0; is < 2; ++is) {
            int o = is * 4096 + tid * 16;       // byte offset in 8KB tile
            int r = o >> 6;                      // row 0..127
            int c = (o & 63) >> 1;               // ushort col in row
            size_t ge = (size_t)r * K_ + kt + c;
            gload16(gAh + ge, (char*)lAh + o);
            gload16(gAl + ge, (char*)lAl + o);
            gload16(gBh + ge, (char*)lBh + o);
            gload16(gBl + ge, (char*)lBl + o);
        }
        __syncthreads();
        bf16x8 ah[4], al[4], bh[4], bl[4];
#pragma unroll
        for (int f = 0; f < 4; ++f) {
            int ea = (wm + f * 16 + fr) * 32 + kh * 8;
            int eb = (wn + f * 16 + fr) * 32 + kh * 8;
            ah[f] = *(const bf16x8*)&lAh[ea];
            al[f] = *(const bf16x8*)&lAl[ea];
            bh[f] = *(const bf16x8*)&lBh[eb];
            bl[f] = *(const bf16x8*)&lBl[eb];
        }
#pragma unroll
        for (int i = 0; i < 4; ++i)
#pragma unroll
            for (int j = 0; j < 4; ++j) {
                acc[i][j] = __builtin_amdgcn_mfma_f32_16x16x32_bf16(ah[i], bh[j], acc[i][j], 0, 0, 0);
                acc[i][j] = __builtin_amdgcn_mfma_f32_16x16x32_bf16(ah[i], bl[j], acc[i][j], 0, 0, 0);
                acc[i][j] = __builtin_amdgcn_mfma_f32_16x16x32_bf16(al[i], bh[j], acc[i][j], 0, 0, 0);
            }
        __syncthreads();
    }

    const float* bias = (nt < 2) ? bfv : btv;
    int nb0 = nt * 128 - ((nt < 2) ? 0 : 256);
#pragma unroll
    for (int j = 0; j < 4; ++j) {
        int ncol = nt * 128 + wn + j * 16 + fr;
        float bv = bias[nb0 + wn + j * 16 + fr];
#pragma unroll
        for (int i = 0; i < 4; ++i) {
            int mrow = mt * 128 + wm + i * 16 + kh * 4;
#pragma unroll
            for (int r = 0; r < 4; ++r) {
                C[(size_t)(mrow + r) * N_ + ncol] = acc[i][j][r] + bv;
            }
        }
    }
}

// ---- gather + relu-dot: out[b][v] ----
__global__ __launch_bounds__(1024) void out_kernel(
    const float* __restrict__ C, const float* __restrict__ gp,
    const float* __restrict__ promo_tab, const float* __restrict__ Wsv,
    const float* __restrict__ bsv,
    const int* __restrict__ from_sqs, const int* __restrict__ to_sqs,
    const int* __restrict__ ptypes, float* __restrict__ out) {
    __shared__ float cb[NSQ * N_];       // 128 KB: fp|tp rows of this b
    __shared__ float gpl[ND];
    __shared__ float wsl[ND];
    __shared__ float pl[5 * ND];
    __shared__ int fsq[NV], tsq[NV], pty[NV];   // 22.3 KB move tables
    int b = blockIdx.x;
    int tid = threadIdx.x;
    const float4* src = (const float4*)(C + (size_t)b * NSQ * N_);
    float4* dst = (float4*)cb;
#pragma unroll
    for (int i = 0; i < 8; ++i) dst[tid + i * 1024] = src[tid + i * 1024];
    if (tid < 64) ((float4*)gpl)[tid] = ((const float4*)(gp + (size_t)b * ND))[tid];
    else if (tid < 128) ((float4*)wsl)[tid - 64] = ((const float4*)Wsv)[tid - 64];
    else if (tid < 448) ((float4*)pl)[tid - 128] = ((const float4*)promo_tab)[tid - 128];
    for (int v = tid; v < NV; v += 1024) {
        fsq[v] = from_sqs[v];
        tsq[v] = to_sqs[v];
        pty[v] = ptypes[v];
    }
    __syncthreads();

    int wave = tid >> 6, lane = tid & 63;
    float bias0 = bsv[0];
    const float4* cb4 = (const float4*)cb;
    const float4* gp4 = (const float4*)gpl;
    const float4* ws4 = (const float4*)wsl;
    const float4* pl4 = (const float4*)pl;
    for (int v = wave; v < NV; v += 16) {
        int sf = fsq[v];
        int st = tsq[v];
        int p  = pty[v];
        float4 a = cb4[sf * 128 + lane];           // fp cols 0..255
        float4 t = cb4[st * 128 + 64 + lane];      // tp cols 256..511
        float4 g = gp4[lane];
        float4 pp = pl4[p * 64 + lane];
        float4 w = ws4[lane];
        float c0 = a.x * t.x + g.x + pp.x;
        float c1 = a.y * t.y + g.y + pp.y;
        float c2 = a.z * t.z + g.z + pp.z;
        float c3 = a.w * t.w + g.w + pp.w;
        float s = fmaxf(c0, 0.f) * w.x + fmaxf(c1, 0.f) * w.y +
                  fmaxf(c2, 0.f) * w.z + fmaxf(c3, 0.f) * w.w;
#pragma unroll
        for (int o = 32; o > 0; o >>= 1) s += __shfl_xor(s, o, 64);
        if (lane == 0) out[(size_t)b * NV + v] = s + bias0;
    }
}

extern "C" void kernel_launch(void* const* d_in, const int* in_sizes, int n_in,
                              void* d_out, int out_size, void* d_ws, size_t ws_size,
                              hipStream_t stream) {
    (void)in_sizes; (void)n_in; (void)out_size; (void)ws_size;
    const float* hid   = (const float*)d_in[0];
    const float* Wf    = (const float*)d_in[1];
    const float* bfv   = (const float*)d_in[2];
    const float* Wt    = (const float*)d_in[3];
    const float* btv   = (const float*)d_in[4];
    const float* Wg    = (const float*)d_in[5];
    const float* bgv   = (const float*)d_in[6];
    const float* promo = (const float*)d_in[7];
    const float* Wsv   = (const float*)d_in[8];
    const float* bsv   = (const float*)d_in[9];
    const int* from_sqs = (const int*)d_in[10];
    const int* to_sqs   = (const int*)d_in[11];
    const int* ptypes   = (const int*)d_in[12];
    float* out = (float*)d_out;

    char* ws = (char*)d_ws;
    // layout: Ahi 32MiB | Alo 32MiB | Whi 1MiB | Wlo 1MiB | C 32MiB | gp 256KiB
    unsigned short* Ahi = (unsigned short*)(ws);
    unsigned short* Alo = (unsigned short*)(ws + 33554432);
    unsigned short* Whi = (unsigned short*)(ws + 67108864);
    unsigned short* Wlo = (unsigned short*)(ws + 68157440);
    float* C  = (float*)(ws + 69206016);
    float* gp = (float*)(ws + 102760448);

    cast_kernel<<<16896, 256, 0, stream>>>(hid, Wf, Wt, Ahi, Alo, Whi, Wlo);
    gp_kernel<<<256, 1024, 0, stream>>>(hid, Wg, bgv, gp);
    gemm3_kernel<<<512, 256, 0, stream>>>(Ahi, Alo, Whi, Wlo, bfv, btv, C);
    out_kernel<<<256, 1024, 0, stream>>>(C, gp, promo, Wsv, bsv,
                                         from_sqs, to_sqs, ptypes, out);
}